// Round 2
// baseline (490.715 us; speedup 1.0000x reference)
//
#include <hip/hip_runtime.h>
#include <hip/hip_bf16.h>
#include <stdint.h>

typedef unsigned short u16;
typedef __attribute__((ext_vector_type(8))) short short8;   // bf16x8 MFMA operand (4 VGPRs)
typedef __attribute__((ext_vector_type(4))) float f32x4;    // MFMA accumulator

#define NSEQ 512
#define PLANE (NSEQ*NSEQ)      // 262144 elems per channel plane
#define CH 128                 // C == H == 128
#define MTOT ((size_t)NSEQ*NSEQ)

__device__ __forceinline__ u16 f2bf(float f){
  __hip_bfloat16 h = __float2bfloat16(f);
  return *reinterpret_cast<u16*>(&h);
}
__device__ __forceinline__ float bf2f(u16 u){
  union { unsigned int i; float f; } x; x.i = ((unsigned int)u) << 16; return x.f;
}
__device__ __forceinline__ float sigmf(float x){ return 1.0f/(1.0f + __expf(-x)); }

// async global->LDS, 16B per lane. LDS dest must be wave-uniform base (HW adds lane*16).
__device__ __forceinline__ void ldg_lds16(const void* g, void* l){
  __builtin_amdgcn_global_load_lds((const __attribute__((address_space(1))) void*)g,
                                   (__attribute__((address_space(3))) void*)l, 16, 0, 0);
}

// ---------------- k1: LayerNorm over C=128, fp32 -> bf16 -------------------
// one wave per row; block = 4 rows
__global__ __launch_bounds__(256) void k1_lnin(const float* __restrict__ x,
        const float* __restrict__ w, const float* __restrict__ b,
        u16* __restrict__ xn){
  int row  = blockIdx.x*4 + (threadIdx.x>>6);
  int lane = threadIdx.x & 63;
  const float* xr = x + (size_t)row*CH;
  float2 v = *reinterpret_cast<const float2*>(&xr[lane*2]);
  float s  = v.x + v.y;
  float s2 = v.x*v.x + v.y*v.y;
  #pragma unroll
  for(int off=32; off>0; off>>=1){ s += __shfl_xor(s, off); s2 += __shfl_xor(s2, off); }
  float mean = s*(1.f/CH);
  float rstd = rsqrtf(s2*(1.f/CH) - mean*mean + 1e-5f);
  float2 wv = *reinterpret_cast<const float2*>(&w[lane*2]);
  float2 bv = *reinterpret_cast<const float2*>(&b[lane*2]);
  ushort2 o;
  o.x = f2bf((v.x-mean)*rstd*wv.x + bv.x);
  o.y = f2bf((v.y-mean)*rstd*wv.y + bv.y);
  *reinterpret_cast<ushort2*>(&xn[(size_t)row*CH + lane*2]) = o;
}

// ---------------- pack weights fp32 -> bf16 --------------------------------
__global__ __launch_bounds__(256) void kpack(const float* __restrict__ pw,
        const float* __restrict__ gw, const float* __restrict__ pow_,
        const float* __restrict__ gow, u16* wp, u16* wg, u16* wpo, u16* wgo){
  int i = blockIdx.x*256 + threadIdx.x;      // 32768 threads
  wp[i] = f2bf(pw[i]);
  wg[i] = f2bf(gw[i]);
  if(i < 128*128){ wpo[i] = f2bf(pow_[i]); wgo[i] = f2bf(gow[i]); }
}

// ---------------- k2: projections + gate -> a/b channel planes -------------
// A = xn [M][128]; Bp = p_in_w rows, Bg = g_in_w rows (dual accumulator so
// h = p*sigmoid(g) pairs per-lane). Block: 128 m x 64 channels.
__global__ __launch_bounds__(256) void k2_proj(const u16* __restrict__ xn,
        const u16* __restrict__ wp, const u16* __restrict__ wg,
        u16* __restrict__ apl, u16* __restrict__ bplanes){
  __shared__ u16 Al[128*64], Bp[64*64], Bg[64*64];    // 32 KB
  const int tid = threadIdx.x, wave = tid>>6, lane = tid&63;
  const int r = lane&15, g = lane>>4;
  const int wm = (wave>>1)*64, wn = (wave&1)*32;
  const size_t m0 = (size_t)blockIdx.x*128;
  const int c0 = blockIdx.y*64;
  f32x4 accp[4][2] = {}; f32x4 accg[4][2] = {};
  for(int k0=0; k0<CH; k0+=64){
    __syncthreads();
    #pragma unroll
    for(int it=0; it<4; ++it)
      ldg_lds16(xn + (m0 + it*32 + (tid>>3))*CH + k0 + (tid&7)*8, &Al[it*2048 + wave*512]);
    #pragma unroll
    for(int it=0; it<2; ++it){
      ldg_lds16(wp + (size_t)(c0 + it*32 + (tid>>3))*CH + k0 + (tid&7)*8, &Bp[it*2048 + wave*512]);
      ldg_lds16(wg + (size_t)(c0 + it*32 + (tid>>3))*CH + k0 + (tid&7)*8, &Bg[it*2048 + wave*512]);
    }
    __syncthreads();
    #pragma unroll
    for(int kk=0; kk<2; ++kk){
      short8 af[4], bpf[2], bgf[2];
      #pragma unroll
      for(int mi=0;mi<4;++mi)
        af[mi] = *reinterpret_cast<const short8*>(&Al[(wm+mi*16+r)*64 + kk*32 + g*8]);
      #pragma unroll
      for(int ni=0;ni<2;++ni){
        bpf[ni] = *reinterpret_cast<const short8*>(&Bp[(wn+ni*16+r)*64 + kk*32 + g*8]);
        bgf[ni] = *reinterpret_cast<const short8*>(&Bg[(wn+ni*16+r)*64 + kk*32 + g*8]);
      }
      #pragma unroll
      for(int mi=0;mi<4;++mi)
        #pragma unroll
        for(int ni=0;ni<2;++ni){
          accp[mi][ni] = __builtin_amdgcn_mfma_f32_16x16x32_bf16(af[mi], bpf[ni], accp[mi][ni],0,0,0);
          accg[mi][ni] = __builtin_amdgcn_mfma_f32_16x16x32_bf16(af[mi], bgf[ni], accg[mi][ni],0,0,0);
        }
    }
  }
  // epilogue: channel c -> plane (a if c<128 else b), position m (4 consecutive per lane)
  #pragma unroll
  for(int mi=0;mi<4;++mi)
    #pragma unroll
    for(int ni=0;ni<2;++ni){
      int c = c0 + wn + ni*16 + r;
      size_t m = m0 + wm + mi*16 + g*4;
      u16* plane = (c < CH) ? (apl + (size_t)c*MTOT) : (bplanes + (size_t)(c-CH)*MTOT);
      ushort4 pk;
      pk.x = f2bf(accp[mi][ni][0] * sigmf(accg[mi][ni][0]));
      pk.y = f2bf(accp[mi][ni][1] * sigmf(accg[mi][ni][1]));
      pk.z = f2bf(accp[mi][ni][2] * sigmf(accg[mi][ni][2]));
      pk.w = f2bf(accp[mi][ni][3] * sigmf(accg[mi][ni][3]));
      *reinterpret_cast<ushort4*>(plane + m) = pk;
    }
}

// ---------------- k3: batched einsum: per h, O = A * B^T -------------------
// A_h, B_h: [512][512] bf16 planes (k contiguous -> natural NT MFMA layout)
__global__ __launch_bounds__(256) void k3_einsum(const u16* __restrict__ apl,
        const u16* __restrict__ bplanes, u16* __restrict__ opl){
  __shared__ u16 Al[128*64], Bl[128*64];              // 32 KB
  const int tid = threadIdx.x, wave = tid>>6, lane = tid&63;
  const int r = lane&15, g = lane>>4;
  const int wm = (wave>>1)*64, wn = (wave&1)*64;
  const int h = blockIdx.y;
  const int i0 = (blockIdx.x>>2)*128, j0 = (blockIdx.x&3)*128;
  const u16* A = apl     + (size_t)h*MTOT;
  const u16* B = bplanes + (size_t)h*MTOT;
  u16* O = opl + (size_t)h*MTOT;
  f32x4 acc[4][4] = {};
  for(int k0=0; k0<NSEQ; k0+=64){
    __syncthreads();
    #pragma unroll
    for(int it=0; it<4; ++it){
      ldg_lds16(A + (size_t)(i0 + it*32 + (tid>>3))*NSEQ + k0 + (tid&7)*8, &Al[it*2048 + wave*512]);
      ldg_lds16(B + (size_t)(j0 + it*32 + (tid>>3))*NSEQ + k0 + (tid&7)*8, &Bl[it*2048 + wave*512]);
    }
    __syncthreads();
    #pragma unroll
    for(int kk=0; kk<2; ++kk){
      short8 af[4], bf[4];
      #pragma unroll
      for(int mi=0;mi<4;++mi)
        af[mi] = *reinterpret_cast<const short8*>(&Al[(wm+mi*16+r)*64 + kk*32 + g*8]);
      #pragma unroll
      for(int ni=0;ni<4;++ni)
        bf[ni] = *reinterpret_cast<const short8*>(&Bl[(wn+ni*16+r)*64 + kk*32 + g*8]);
      #pragma unroll
      for(int mi=0;mi<4;++mi)
        #pragma unroll
        for(int ni=0;ni<4;++ni)
          acc[mi][ni] = __builtin_amdgcn_mfma_f32_16x16x32_bf16(af[mi], bf[ni], acc[mi][ni],0,0,0);
    }
  }
  #pragma unroll
  for(int mi=0;mi<4;++mi)
    #pragma unroll
    for(int ni=0;ni<4;++ni){
      int ib = i0 + wm + mi*16 + g*4;
      int j  = j0 + wn + ni*16 + r;
      #pragma unroll
      for(int v=0;v<4;++v)
        O[(size_t)(ib+v)*NSEQ + j] = f2bf(acc[mi][ni][v]);
    }
}

// ---------------- k4a: [h][i][j] -> [i][j][h] transpose + LayerNorm --------
// block: one i, 128 j's, all 128 h
__global__ __launch_bounds__(256) void k4a_lnout(const u16* __restrict__ opl,
        const float* __restrict__ w, const float* __restrict__ b,
        u16* __restrict__ onorm){
  __shared__ u16 S[128*136];                           // padded rows
  const int tid = threadIdx.x;
  const int i = blockIdx.y, j0 = blockIdx.x*128;
  #pragma unroll
  for(int rep=0; rep<8; ++rep){
    int hh = rep*16 + (tid>>4), ck = tid&15;
    *reinterpret_cast<short8*>(&S[hh*136 + ck*8]) =
      *reinterpret_cast<const short8*>(opl + (size_t)hh*MTOT + (size_t)i*NSEQ + j0 + ck*8);
  }
  __syncthreads();
  if(tid < 128){
    int j = tid;
    float s=0.f, s2=0.f;
    for(int hh=0; hh<128; ++hh){
      float xv = bf2f(S[hh*136 + j]); s += xv; s2 += xv*xv;
    }
    float mean = s*(1.f/128.f);
    float rstd = rsqrtf(s2*(1.f/128.f) - mean*mean + 1e-5f);
    u16* dst = onorm + ((size_t)i*NSEQ + j0 + j)*CH;
    for(int h0=0; h0<128; h0+=8){
      short8 pk;
      #pragma unroll
      for(int t=0;t<8;++t){
        int hh = h0+t;
        float xv = bf2f(S[hh*136 + j]);
        pk[t] = (short)f2bf((xv-mean)*rstd*w[hh] + b[hh]);
      }
      *reinterpret_cast<short8*>(&dst[h0]) = pk;
    }
  }
}

// ---------------- k4b: out = (o_norm @ Wpo^T) * sigmoid(xn @ Wgo^T) --------
__global__ __launch_bounds__(256) void k4b_out(const u16* __restrict__ onorm,
        const u16* __restrict__ xn, const u16* __restrict__ wpo,
        const u16* __restrict__ wgo, float* __restrict__ out){
  __shared__ u16 A1[128*64], A2[128*64], B1[64*64], B2[64*64];  // 48 KB
  const int tid = threadIdx.x, wave = tid>>6, lane = tid&63;
  const int r = lane&15, g = lane>>4;
  const int wm = (wave>>1)*64, wn = (wave&1)*32;
  const size_t m0 = (size_t)blockIdx.x*128;
  const int n0 = blockIdx.y*64;
  f32x4 accp[4][2] = {}; f32x4 accg[4][2] = {};
  for(int k0=0; k0<CH; k0+=64){
    __syncthreads();
    #pragma unroll
    for(int it=0; it<4; ++it){
      ldg_lds16(onorm + (m0 + it*32 + (tid>>3))*CH + k0 + (tid&7)*8, &A1[it*2048 + wave*512]);
      ldg_lds16(xn    + (m0 + it*32 + (tid>>3))*CH + k0 + (tid&7)*8, &A2[it*2048 + wave*512]);
    }
    #pragma unroll
    for(int it=0; it<2; ++it){
      ldg_lds16(wpo + (size_t)(n0 + it*32 + (tid>>3))*CH + k0 + (tid&7)*8, &B1[it*2048 + wave*512]);
      ldg_lds16(wgo + (size_t)(n0 + it*32 + (tid>>3))*CH + k0 + (tid&7)*8, &B2[it*2048 + wave*512]);
    }
    __syncthreads();
    #pragma unroll
    for(int kk=0; kk<2; ++kk){
      short8 a1f[4], a2f[4], b1f[2], b2f[2];
      #pragma unroll
      for(int mi=0;mi<4;++mi){
        a1f[mi] = *reinterpret_cast<const short8*>(&A1[(wm+mi*16+r)*64 + kk*32 + g*8]);
        a2f[mi] = *reinterpret_cast<const short8*>(&A2[(wm+mi*16+r)*64 + kk*32 + g*8]);
      }
      #pragma unroll
      for(int ni=0;ni<2;++ni){
        b1f[ni] = *reinterpret_cast<const short8*>(&B1[(wn+ni*16+r)*64 + kk*32 + g*8]);
        b2f[ni] = *reinterpret_cast<const short8*>(&B2[(wn+ni*16+r)*64 + kk*32 + g*8]);
      }
      #pragma unroll
      for(int mi=0;mi<4;++mi)
        #pragma unroll
        for(int ni=0;ni<2;++ni){
          accp[mi][ni] = __builtin_amdgcn_mfma_f32_16x16x32_bf16(a1f[mi], b1f[ni], accp[mi][ni],0,0,0);
          accg[mi][ni] = __builtin_amdgcn_mfma_f32_16x16x32_bf16(a2f[mi], b2f[ni], accg[mi][ni],0,0,0);
        }
    }
  }
  #pragma unroll
  for(int mi=0;mi<4;++mi)
    #pragma unroll
    for(int ni=0;ni<2;++ni){
      int n = n0 + wn + ni*16 + r;
      size_t m = m0 + wm + mi*16 + g*4;
      #pragma unroll
      for(int v=0;v<4;++v)
        out[(m+v)*CH + n] = accp[mi][ni][v] * sigmf(accg[mi][ni][v]);
    }
}

extern "C" void kernel_launch(void* const* d_in, const int* in_sizes, int n_in,
                              void* d_out, int out_size, void* d_ws, size_t ws_size,
                              hipStream_t stream){
  const float* x       = (const float*)d_in[0];
  const float* nw_in   = (const float*)d_in[1];
  const float* nb_in   = (const float*)d_in[2];
  const float* p_in_w  = (const float*)d_in[3];
  const float* g_in_w  = (const float*)d_in[4];
  const float* nw_out  = (const float*)d_in[5];
  const float* nb_out  = (const float*)d_in[6];
  const float* p_out_w = (const float*)d_in[7];
  const float* g_out_w = (const float*)d_in[8];
  float* out = (float*)d_out;

  // ws layout (bf16 buffers), total ~201.5 MB:
  const size_t SZ = MTOT*CH*sizeof(u16);   // 67108864
  char* ws = (char*)d_ws;
  u16* xn      = (u16*)ws;                 // x_norm_in [M][128]
  u16* apl     = (u16*)(ws + SZ);          // a planes [128][M]; reused as o_norm [M][128] after k3
  u16* bplanes = (u16*)(ws + 2*SZ);        // b planes [128][M]
  u16* wpb     = (u16*)(ws + 3*SZ);        // packed weights bf16
  u16* wgb     = wpb + 256*128;
  u16* wpob    = wgb + 256*128;
  u16* wgob    = wpob + 128*128;
  u16* opl     = (u16*)d_out;              // o planes bf16 live in d_out's first 67MB (fully rewritten by k4b)
  u16* onorm   = apl;                      // alias: a/b planes dead after k3

  kpack <<<128, 256, 0, stream>>>(p_in_w, g_in_w, p_out_w, g_out_w, wpb, wgb, wpob, wgob);
  k1_lnin<<<65536, 256, 0, stream>>>(x, nw_in, nb_in, xn);
  k2_proj<<<dim3(2048,4), 256, 0, stream>>>(xn, wpb, wgb, apl, bplanes);
  k3_einsum<<<dim3(16,128), 256, 0, stream>>>(apl, bplanes, opl);
  k4a_lnout<<<dim3(4,512), 256, 0, stream>>>(opl, nw_out, nb_out, onorm);
  k4b_out<<<dim3(2048,2), 256, 0, stream>>>(onorm, xn, wpob, wgob, out);
}

// Round 4
// 476.238 us; speedup vs baseline: 1.0304x; 1.0304x over previous
//
#include <hip/hip_runtime.h>
#include <hip/hip_bf16.h>
#include <stdint.h>

typedef unsigned short u16;
typedef __attribute__((ext_vector_type(8))) short short8;   // bf16x8 MFMA operand (4 VGPRs)
typedef __attribute__((ext_vector_type(4))) float f32x4;    // MFMA accumulator

#define NSEQ 512
#define CH 128                 // C == H == 128
#define MTOT ((size_t)NSEQ*NSEQ)

__device__ __forceinline__ u16 f2bf(float f){
  __hip_bfloat16 h = __float2bfloat16(f);
  return *reinterpret_cast<u16*>(&h);
}
__device__ __forceinline__ float bf2f(u16 u){
  union { unsigned int i; float f; } x; x.i = ((unsigned int)u) << 16; return x.f;
}
__device__ __forceinline__ float sigmf(float x){ return 1.0f/(1.0f + __expf(-x)); }

// async global->LDS, 16B per lane. LDS dest must be wave-uniform base (HW adds lane*16).
__device__ __forceinline__ void ldg_lds16(const void* g, void* l){
  __builtin_amdgcn_global_load_lds((const __attribute__((address_space(1))) void*)g,
                                   (__attribute__((address_space(3))) void*)l, 16, 0, 0);
}

// ---------------- k1: LayerNorm over C=128, fp32 -> bf16 -------------------
// half-wave (32 lanes) per row, float4 loads; grid-stride, 4096 blocks x 8 iters
__global__ __launch_bounds__(256) void k1_lnin(const float* __restrict__ x,
        const float* __restrict__ w, const float* __restrict__ b,
        u16* __restrict__ xn){
  const int l32 = threadIdx.x & 31;
  const float4 wv = *reinterpret_cast<const float4*>(&w[l32*4]);
  const float4 bv = *reinterpret_cast<const float4*>(&b[l32*4]);
  for(int rp=0; rp<8; ++rp){
    size_t row = ((size_t)rp*4096 + blockIdx.x)*8 + (threadIdx.x>>5);
    float4 v = *reinterpret_cast<const float4*>(&x[row*CH + l32*4]);
    float s  = v.x+v.y+v.z+v.w;
    float s2 = v.x*v.x + v.y*v.y + v.z*v.z + v.w*v.w;
    #pragma unroll
    for(int off=16; off>0; off>>=1){ s += __shfl_xor(s, off); s2 += __shfl_xor(s2, off); }
    float mean = s*(1.f/CH);
    float rstd = rsqrtf(s2*(1.f/CH) - mean*mean + 1e-5f);
    ushort4 o;
    o.x = f2bf((v.x-mean)*rstd*wv.x + bv.x);
    o.y = f2bf((v.y-mean)*rstd*wv.y + bv.y);
    o.z = f2bf((v.z-mean)*rstd*wv.z + bv.z);
    o.w = f2bf((v.w-mean)*rstd*wv.w + bv.w);
    *reinterpret_cast<ushort4*>(&xn[row*CH + l32*4]) = o;
  }
}

// ---------------- pack weights fp32 -> bf16 --------------------------------
__global__ __launch_bounds__(256) void kpack(const float* __restrict__ pw,
        const float* __restrict__ gw, const float* __restrict__ pow_,
        const float* __restrict__ gow, u16* wp, u16* wg, u16* wpo, u16* wgo){
  int i = blockIdx.x*256 + threadIdx.x;      // 32768 threads
  wp[i] = f2bf(pw[i]);
  wg[i] = f2bf(gw[i]);
  if(i < 128*128){ wpo[i] = f2bf(pow_[i]); wgo[i] = f2bf(gow[i]); }
}

// ---------------- k2: projections + gate -> a/b channel planes -------------
// XCD-chunked grid: same x (xn tile) with its 4 y-slices adjacent on one XCD.
// Epilogue restaged via LDS -> 16B coalesced plane stores.
__global__ __launch_bounds__(256) void k2_proj(const u16* __restrict__ xn,
        const u16* __restrict__ wp, const u16* __restrict__ wg,
        u16* __restrict__ apl, u16* __restrict__ bplanes){
  __shared__ __align__(16) u16 SM[16384];     // Al 8192 | Bp 4096 | Bg 4096 ; E overlays (64*136=8704)
  u16* Al = SM; u16* Bp = SM + 8192; u16* Bg = SM + 12288;
  const int tid = threadIdx.x, wave = tid>>6, lane = tid&63;
  const int r = lane&15, g = lane>>4;
  const int wm = (wave>>1)*64, wn = (wave&1)*32;
  // bijective XCD chunking (nwg=8192): xcd = bid&7 gets logical [xcd*1024, +1024)
  const int bid = blockIdx.x;
  const int l   = (bid&7)*1024 + (bid>>3);
  const int y   = l&3;                 // weight slice
  const size_t m0 = (size_t)(l>>2)*128;
  const int c0 = y*64;
  f32x4 accp[4][2] = {}; f32x4 accg[4][2] = {};
  for(int k0=0; k0<CH; k0+=64){
    __syncthreads();
    #pragma unroll
    for(int it=0; it<4; ++it)
      ldg_lds16(xn + (m0 + it*32 + (tid>>3))*CH + k0 + (tid&7)*8, &Al[it*2048 + wave*512]);
    #pragma unroll
    for(int it=0; it<2; ++it){
      ldg_lds16(wp + (size_t)(c0 + it*32 + (tid>>3))*CH + k0 + (tid&7)*8, &Bp[it*2048 + wave*512]);
      ldg_lds16(wg + (size_t)(c0 + it*32 + (tid>>3))*CH + k0 + (tid&7)*8, &Bg[it*2048 + wave*512]);
    }
    __syncthreads();
    #pragma unroll
    for(int kk=0; kk<2; ++kk){
      short8 af[4], bpf[2], bgf[2];
      #pragma unroll
      for(int mi=0;mi<4;++mi)
        af[mi] = *reinterpret_cast<const short8*>(&Al[(wm+mi*16+r)*64 + kk*32 + g*8]);
      #pragma unroll
      for(int ni=0;ni<2;++ni){
        bpf[ni] = *reinterpret_cast<const short8*>(&Bp[(wn+ni*16+r)*64 + kk*32 + g*8]);
        bgf[ni] = *reinterpret_cast<const short8*>(&Bg[(wn+ni*16+r)*64 + kk*32 + g*8]);
      }
      #pragma unroll
      for(int mi=0;mi<4;++mi)
        #pragma unroll
        for(int ni=0;ni<2;++ni){
          accp[mi][ni] = __builtin_amdgcn_mfma_f32_16x16x32_bf16(af[mi], bpf[ni], accp[mi][ni],0,0,0);
          accg[mi][ni] = __builtin_amdgcn_mfma_f32_16x16x32_bf16(af[mi], bgf[ni], accg[mi][ni],0,0,0);
        }
    }
  }
  // epilogue: acc -> LDS E[c][m] (stride 136), then coalesced 16B plane stores
  __syncthreads();
  #pragma unroll
  for(int mi=0;mi<4;++mi)
    #pragma unroll
    for(int ni=0;ni<2;++ni){
      int cl = wn + ni*16 + r;
      int ml = wm + mi*16 + g*4;
      ushort4 pk;
      pk.x = f2bf(accp[mi][ni][0] * sigmf(accg[mi][ni][0]));
      pk.y = f2bf(accp[mi][ni][1] * sigmf(accg[mi][ni][1]));
      pk.z = f2bf(accp[mi][ni][2] * sigmf(accg[mi][ni][2]));
      pk.w = f2bf(accp[mi][ni][3] * sigmf(accg[mi][ni][3]));
      *reinterpret_cast<ushort4*>(&SM[cl*136 + ml]) = pk;
    }
  __syncthreads();
  #pragma unroll
  for(int e=0;e<4;++e){
    int idx = e*256 + tid;
    int c = idx>>4, chk = idx&15;
    int cg = c0 + c;
    u16* plane = (cg < CH) ? (apl + (size_t)cg*MTOT) : (bplanes + (size_t)(cg-CH)*MTOT);
    *reinterpret_cast<short8*>(plane + m0 + chk*8) =
      *reinterpret_cast<const short8*>(&SM[c*136 + chk*8]);
  }
}

// ---------------- k3: batched einsum: per h, O = A * B^T -------------------
// XCD-chunked by h (each XCD owns 16 planes -> per-h A/B fetched once per XCD).
// Epilogue restaged via LDS -> 16B stores.
__global__ __launch_bounds__(256) void k3_einsum(const u16* __restrict__ apl,
        const u16* __restrict__ bplanes, u16* __restrict__ opl){
  __shared__ __align__(16) u16 SM[17408];     // Al 8192 | Bl 8192 ; E overlays (128*136=17408)
  u16* Al = SM; u16* Bl = SM + 8192;
  const int tid = threadIdx.x, wave = tid>>6, lane = tid&63;
  const int r = lane&15, g = lane>>4;
  const int wm = (wave>>1)*64, wn = (wave&1)*64;
  // chunking (nwg=2048): logical l -> h = l>>4 (16 consecutive h per XCD), ij = l&15
  const int bid = blockIdx.x;
  const int l   = (bid&7)*256 + (bid>>3);
  const int h   = l>>4, ij = l&15;
  const int i0  = (ij>>2)*128, j0 = (ij&3)*128;
  const u16* A = apl     + (size_t)h*MTOT;
  const u16* B = bplanes + (size_t)h*MTOT;
  u16* O = opl + (size_t)h*MTOT;
  f32x4 acc[4][4] = {};
  for(int k0=0; k0<NSEQ; k0+=64){
    __syncthreads();
    #pragma unroll
    for(int it=0; it<4; ++it){
      ldg_lds16(A + (size_t)(i0 + it*32 + (tid>>3))*NSEQ + k0 + (tid&7)*8, &Al[it*2048 + wave*512]);
      ldg_lds16(B + (size_t)(j0 + it*32 + (tid>>3))*NSEQ + k0 + (tid&7)*8, &Bl[it*2048 + wave*512]);
    }
    __syncthreads();
    #pragma unroll
    for(int kk=0; kk<2; ++kk){
      short8 af[4], bf[4];
      #pragma unroll
      for(int mi=0;mi<4;++mi)
        af[mi] = *reinterpret_cast<const short8*>(&Al[(wm+mi*16+r)*64 + kk*32 + g*8]);
      #pragma unroll
      for(int ni=0;ni<4;++ni)
        bf[ni] = *reinterpret_cast<const short8*>(&Bl[(wn+ni*16+r)*64 + kk*32 + g*8]);
      #pragma unroll
      for(int mi=0;mi<4;++mi)
        #pragma unroll
        for(int ni=0;ni<4;++ni)
          acc[mi][ni] = __builtin_amdgcn_mfma_f32_16x16x32_bf16(af[mi], bf[ni], acc[mi][ni],0,0,0);
    }
  }
  // epilogue: acc -> LDS E[i][j] (stride 136) -> coalesced short8 stores
  __syncthreads();
  #pragma unroll
  for(int mi=0;mi<4;++mi)
    #pragma unroll
    for(int ni=0;ni<4;++ni){
      int row = wm + mi*16 + g*4;
      int col = wn + ni*16 + r;
      #pragma unroll
      for(int v=0;v<4;++v)
        SM[(row+v)*136 + col] = f2bf(acc[mi][ni][v]);
    }
  __syncthreads();
  #pragma unroll
  for(int e=0;e<8;++e){
    int idx = e*256 + tid;
    int row = idx>>4, chk = idx&15;
    *reinterpret_cast<short8*>(O + (size_t)(i0+row)*NSEQ + j0 + chk*8) =
      *reinterpret_cast<const short8*>(&SM[row*136 + chk*8]);
  }
}

// ---------------- k4a: [h][i][j] -> [i][j][h] transpose + LayerNorm --------
// 2 i-rows per block -> all 256 threads active in LN/store phase
__global__ __launch_bounds__(256) void k4a_lnout(const u16* __restrict__ opl,
        const float* __restrict__ w, const float* __restrict__ b,
        u16* __restrict__ onorm){
  __shared__ __align__(16) u16 S[2*128*144];           // 72 KB, stride 144 (conflict-free b128 writes)
  const int tid = threadIdx.x;
  const int i = blockIdx.y*2, j0 = blockIdx.x*128;
  #pragma unroll
  for(int rep=0; rep<16; ++rep){
    int half = rep>>3, rr = rep&7;
    int hh = rr*16 + (tid>>4), ck = tid&15;
    *reinterpret_cast<short8*>(&S[half*18432 + hh*144 + ck*8]) =
      *reinterpret_cast<const short8*>(opl + (size_t)hh*MTOT + (size_t)(i+half)*NSEQ + j0 + ck*8);
  }
  __syncthreads();
  {
    int j = tid&127, half = tid>>7;
    const u16* Sb = &S[half*18432];
    float s=0.f, s2=0.f;
    for(int hh=0; hh<128; ++hh){
      float xv = bf2f(Sb[hh*144 + j]); s += xv; s2 += xv*xv;
    }
    float mean = s*(1.f/128.f);
    float rstd = rsqrtf(s2*(1.f/128.f) - mean*mean + 1e-5f);
    u16* dst = onorm + ((size_t)(i+half)*NSEQ + j0 + j)*CH;
    for(int h0=0; h0<128; h0+=8){
      short8 pk;
      #pragma unroll
      for(int t=0;t<8;++t){
        int hh = h0+t;
        float xv = bf2f(Sb[hh*144 + j]);
        pk[t] = (short)f2bf((xv-mean)*rstd*w[hh] + b[hh]);
      }
      *reinterpret_cast<short8*>(&dst[h0]) = pk;
    }
  }
}

// ---------------- k4b: out = (o_norm @ Wpo^T) * sigmoid(xn @ Wgo^T) --------
// XCD-chunked (y-pairs adjacent -> A tiles fetched once) + fp32 LDS-restaged epilogue
__global__ __launch_bounds__(256) void k4b_out(const u16* __restrict__ onorm,
        const u16* __restrict__ xn, const u16* __restrict__ wpo,
        const u16* __restrict__ wgo, float* __restrict__ out){
  __shared__ __align__(16) u16 SM[24576];     // A1 8192 | A2 8192 | B1 4096 | B2 4096 ; E f32[128][68] overlays
  u16* A1 = SM; u16* A2 = SM + 8192; u16* B1 = SM + 16384; u16* B2 = SM + 20480;
  float* E = (float*)SM;                      // 128*68*4 = 34816 B <= 49152
  const int tid = threadIdx.x, wave = tid>>6, lane = tid&63;
  const int r = lane&15, g = lane>>4;
  const int wm = (wave>>1)*64, wn = (wave&1)*32;
  // chunking (nwg=4096): l = (bid&7)*512 + bid>>3 ; y = l&1, xb = l>>1
  const int bid = blockIdx.x;
  const int l   = (bid&7)*512 + (bid>>3);
  const int y   = l&1;
  const size_t m0 = (size_t)(l>>1)*128;
  const int n0 = y*64;
  f32x4 accp[4][2] = {}; f32x4 accg[4][2] = {};
  for(int k0=0; k0<CH; k0+=64){
    __syncthreads();
    #pragma unroll
    for(int it=0; it<4; ++it){
      ldg_lds16(onorm + (m0 + it*32 + (tid>>3))*CH + k0 + (tid&7)*8, &A1[it*2048 + wave*512]);
      ldg_lds16(xn    + (m0 + it*32 + (tid>>3))*CH + k0 + (tid&7)*8, &A2[it*2048 + wave*512]);
    }
    #pragma unroll
    for(int it=0; it<2; ++it){
      ldg_lds16(wpo + (size_t)(n0 + it*32 + (tid>>3))*CH + k0 + (tid&7)*8, &B1[it*2048 + wave*512]);
      ldg_lds16(wgo + (size_t)(n0 + it*32 + (tid>>3))*CH + k0 + (tid&7)*8, &B2[it*2048 + wave*512]);
    }
    __syncthreads();
    #pragma unroll
    for(int kk=0; kk<2; ++kk){
      short8 a1f[4], a2f[4], b1f[2], b2f[2];
      #pragma unroll
      for(int mi=0;mi<4;++mi){
        a1f[mi] = *reinterpret_cast<const short8*>(&A1[(wm+mi*16+r)*64 + kk*32 + g*8]);
        a2f[mi] = *reinterpret_cast<const short8*>(&A2[(wm+mi*16+r)*64 + kk*32 + g*8]);
      }
      #pragma unroll
      for(int ni=0;ni<2;++ni){
        b1f[ni] = *reinterpret_cast<const short8*>(&B1[(wn+ni*16+r)*64 + kk*32 + g*8]);
        b2f[ni] = *reinterpret_cast<const short8*>(&B2[(wn+ni*16+r)*64 + kk*32 + g*8]);
      }
      #pragma unroll
      for(int mi=0;mi<4;++mi)
        #pragma unroll
        for(int ni=0;ni<2;++ni){
          accp[mi][ni] = __builtin_amdgcn_mfma_f32_16x16x32_bf16(a1f[mi], b1f[ni], accp[mi][ni],0,0,0);
          accg[mi][ni] = __builtin_amdgcn_mfma_f32_16x16x32_bf16(a2f[mi], b2f[ni], accg[mi][ni],0,0,0);
        }
    }
  }
  // epilogue: acc -> LDS E[m][n] f32 (stride 68) -> float4 coalesced stores
  __syncthreads();
  #pragma unroll
  for(int mi=0;mi<4;++mi)
    #pragma unroll
    for(int ni=0;ni<2;++ni){
      int row = wm + mi*16 + g*4;
      int col = wn + ni*16 + r;
      #pragma unroll
      for(int v=0;v<4;++v)
        E[(row+v)*68 + col] = accp[mi][ni][v] * sigmf(accg[mi][ni][v]);
    }
  __syncthreads();
  #pragma unroll
  for(int e=0;e<8;++e){
    int idx = e*256 + tid;
    int row = idx>>4, chk = idx&15;
    *reinterpret_cast<float4*>(out + (m0+row)*CH + n0 + chk*4) =
      *reinterpret_cast<const float4*>(&E[row*68 + chk*4]);
  }
}

extern "C" void kernel_launch(void* const* d_in, const int* in_sizes, int n_in,
                              void* d_out, int out_size, void* d_ws, size_t ws_size,
                              hipStream_t stream){
  const float* x       = (const float*)d_in[0];
  const float* nw_in   = (const float*)d_in[1];
  const float* nb_in   = (const float*)d_in[2];
  const float* p_in_w  = (const float*)d_in[3];
  const float* g_in_w  = (const float*)d_in[4];
  const float* nw_out  = (const float*)d_in[5];
  const float* nb_out  = (const float*)d_in[6];
  const float* p_out_w = (const float*)d_in[7];
  const float* g_out_w = (const float*)d_in[8];
  float* out = (float*)d_out;

  // ws layout (bf16 buffers), total ~201.5 MB:
  const size_t SZ = MTOT*CH*sizeof(u16);   // 67108864
  char* ws = (char*)d_ws;
  u16* xn      = (u16*)ws;                 // x_norm_in [M][128]
  u16* apl     = (u16*)(ws + SZ);          // a planes [128][M]; reused as o_norm [M][128] after k3
  u16* bplanes = (u16*)(ws + 2*SZ);        // b planes [128][M]
  u16* wpb     = (u16*)(ws + 3*SZ);        // packed weights bf16
  u16* wgb     = wpb + 256*128;
  u16* wpob    = wgb + 256*128;
  u16* wgob    = wpob + 128*128;
  u16* opl     = (u16*)d_out;              // o planes bf16 live in d_out's first 67MB (fully rewritten by k4b)
  u16* onorm   = apl;                      // alias: a/b planes dead after k3

  kpack  <<<128, 256, 0, stream>>>(p_in_w, g_in_w, p_out_w, g_out_w, wpb, wgb, wpob, wgob);
  k1_lnin<<<4096, 256, 0, stream>>>(x, nw_in, nb_in, xn);
  k2_proj<<<8192, 256, 0, stream>>>(xn, wpb, wgb, apl, bplanes);
  k3_einsum<<<2048, 256, 0, stream>>>(apl, bplanes, opl);
  k4a_lnout<<<dim3(4,256), 256, 0, stream>>>(opl, nw_out, nb_out, onorm);
  k4b_out<<<4096, 256, 0, stream>>>(onorm, xn, wpob, wgob, out);
}